// Round 10
// baseline (147.615 us; speedup 1.0000x reference)
//
#include <hip/hip_runtime.h>

#define S 2048
#define HID 2048
#define NH 16
#define DH 128
#define VOC 128
#define LCAP 128
#define K2EXP 0.12752551286084112f   // (1/sqrt(128)) * log2(e)
#define RTHR 62.0f                   // defer-max threshold in raw-score units
#define NEGS -3.0e38f

typedef __bf16 bf16_t;
typedef __attribute__((ext_vector_type(8))) __bf16 bf16x8;
typedef __attribute__((ext_vector_type(4))) __bf16 bf16x4;
typedef __attribute__((ext_vector_type(4))) float f32x4;
typedef __attribute__((ext_vector_type(16))) float f32x16;

typedef __attribute__((address_space(1))) unsigned int guint;
typedef __attribute__((address_space(3))) unsigned int luint;

#define MFMA16 __builtin_amdgcn_mfma_f32_16x16x32_bf16
#define MFMA32 __builtin_amdgcn_mfma_f32_32x32x16_bf16

__device__ __forceinline__ void gl_lds16(const void* g, void* l) {
  __builtin_amdgcn_global_load_lds((guint*)(unsigned long long)g,
                                   (luint*)(unsigned)(unsigned long long)l,
                                   16, 0, 0);
}

__device__ __forceinline__ unsigned cvtpk(float lo, float hi) {
  unsigned r;
  asm("v_cvt_pk_bf16_f32 %0, %1, %2" : "=v"(r) : "v"(lo), "v"(hi));
  return r;
}
__device__ __forceinline__ void plswap(unsigned& a, unsigned& b) {
  asm volatile("v_permlane32_swap_b32 %0, %1" : "+v"(a), "+v"(b));
}
__device__ __forceinline__ bf16x8 mk8(unsigned d0, unsigned d1, unsigned d2, unsigned d3) {
  union { unsigned u[4]; bf16x8 v; } x;
  x.u[0] = d0; x.u[1] = d1; x.u[2] = d2; x.u[3] = d3;
  return x.v;
}

// ---------------- mask precompute: intervals + starts + landmarks + 32q-stripe meta ----------------
__global__ __launch_bounds__(256) void maskprep2(const int* __restrict__ tokens,
                                                 const unsigned char* __restrict__ seg,
                                                 const unsigned char* __restrict__ spc,
                                                 int4* __restrict__ mi,
                                                 int* __restrict__ lq,
                                                 unsigned long long* __restrict__ lmask,
                                                 int2* __restrict__ smeta) {
  __shared__ int ssp[257], ssg[257], smw[257], sms[257], sfl[257];
  __shared__ int fpre[2048];
  __shared__ int ns64[64];
  __shared__ unsigned long long lmk[32];
  __shared__ int cdet[2];
  int t = threadIdx.x;
  if (t < 2) cdet[t] = 0;
  if (t < 32) lmk[t] = 0ull;
  __syncthreads();
  {
    int nz = ((t & 3) != 0 && seg[t]) ? 1 : 0;
    int fc = ((t & 3) == 3 && seg[t] == 0x3f) ? 1 : 0;
    if (nz) atomicAdd(&cdet[0], 1);
    if (fc) atomicAdd(&cdet[1], 1);
  }
  __syncthreads();
  int lay = (cdet[1] > 8) ? 2 : ((cdet[0] > 4) ? 1 : 0);
  auto getb = [&](const unsigned char* p, int i) -> int {
    if (lay == 1) return p[i] != 0;
    if (lay == 2) return ((const float*)p)[i] != 0.f;
    return ((const int*)p)[i] != 0;
  };
  int base = t * 8;
  int spv[8], sgv[8], npv[8], fv[8];
  int a = 0, b = 0, mw = 0, ms = 0, fs = 0;
  for (int j = 0; j < 8; j++) {
    int i = base + j;
    spv[j] = getb(spc, i);
    sgv[j] = 1 - getb(seg, i);
    npv[j] = (tokens[i] != 127) ? 1 : 0;
    fv[j] = spv[j] & sgv[j] & npv[j];
    a += spv[j]; b += sgv[j]; fs += fv[j];
    if (i >= 1 && spv[j]) mw = (i + 1 > mw) ? i + 1 : mw;
    if (i >= 1 && sgv[j]) ms = (i + 1 > ms) ? i + 1 : ms;
  }
  ssp[t + 1] = a; ssg[t + 1] = b; smw[t + 1] = mw; sms[t + 1] = ms; sfl[t + 1] = fs;
  if (t == 0) { ssp[0] = 0; ssg[0] = 0; smw[0] = 0; sms[0] = 0; sfl[0] = 0; }
  __syncthreads();
  for (int off = 1; off < 256; off <<= 1) {
    int v0 = 0, v1 = 0, v2 = 0, v3 = 0, v4 = 0;
    if (t + 1 > off) { v0 = ssp[t+1-off]; v1 = ssg[t+1-off]; v2 = smw[t+1-off]; v3 = sms[t+1-off]; v4 = sfl[t+1-off]; }
    __syncthreads();
    ssp[t + 1] += v0; ssg[t + 1] += v1;
    if (v2 > smw[t + 1]) smw[t + 1] = v2;
    if (v3 > sms[t + 1]) sms[t + 1] = v3;
    sfl[t + 1] += v4;
    __syncthreads();
  }
  // per-32q-stripe near-start: exclusive prefix at token 32*(t/4), i.e. index t with t&3==0
  if ((t & 3) == 0) {
    int ws = smw[t], ss = sms[t];
    ns64[t >> 2] = ws < ss ? ws : ss;
  }
  int esp = ssp[t], esg = ssg[t], ef = sfl[t];
  for (int j = 0; j < 8; j++) {
    int i = base + j;
    int wint = (i == 0) ? (1 + spv[j]) : (1 + esp);
    int sint = (i == 0) ? (1 + sgv[j]) : (1 + esg);
    mi[i] = make_int4(npv[j] | (spv[j] << 1) | (sgv[j] << 2), wint, sint, 0);
    fpre[i] = ef;
    int lqv = (fv[j] && ef < LCAP) ? ef : -1;
    lq[i] = lqv;
    if (lqv >= 0) atomicOr(&lmk[i >> 6], 1ull << (i & 63));
    esp += spv[j]; esg += sgv[j]; ef += fv[j];
  }
  __syncthreads();
  if (t < 32) lmask[t] = lmk[t];
  if (t < 64) {
    int nsTile = ns64[t] >> 5;           // 32-kv tile index
    int lc = fpre[nsTile * 32];          // landmarks strictly below near zone
    if (lc > LCAP) lc = LCAP;
    smeta[t] = make_int2(nsTile, lc);
  }
}

// ---------------- full mask bit table: cmask[word][q], word=kv/32 ----------------
__global__ __launch_bounds__(256) void bitgen(const int4* __restrict__ mi,
                                              unsigned* __restrict__ cmask) {
  __shared__ int4 km[32];
  int w = blockIdx.x;
  int t = threadIdx.x;
  int q = blockIdx.y * 256 + t;
  if (t < 32) km[t] = mi[w * 32 + t];
  __syncthreads();
  int4 mq = mi[q];
  unsigned word = 0;
  #pragma unroll
  for (int j = 0; j < 32; j++) {
    int kv = w * 32 + j;
    int4 mk = km[j];
    bool v = ((mq.x & mk.x) & 1) &&
             ((mk.x & 2) || (mq.y == mk.y)) &&
             ((mk.x & 4) || (mq.z == mk.z)) &&
             (kv <= q);
    word |= (v ? 1u : 0u) << j;
  }
  cmask[(size_t)w * S + q] = word;
}

// ---------------- shared transpose-store helper (embed) ----------------
__device__ __forceinline__ void store_h_hT(bf16x8 ob[4], bf16_t* tile, int q0, int h,
                                           int ql, int d0, int tid,
                                           bf16_t* __restrict__ hb, bf16_t* __restrict__ hbT) {
  #pragma unroll
  for (int i = 0; i < 4; i++)
    *(bf16x8*)(hb + (size_t)(q0 + ql) * HID + h * DH + d0 + i * 8) = ob[i];
  #pragma unroll
  for (int i = 0; i < 4; i++)
    #pragma unroll
    for (int j = 0; j < 8; j++) tile[ql * 136 + d0 + i * 8 + j] = ob[i][j];
  __syncthreads();
  int dT = tid >> 1, qh = (tid & 1) * 32;
  bf16x8 tb[4];
  #pragma unroll
  for (int i = 0; i < 4; i++)
    #pragma unroll
    for (int j = 0; j < 8; j++) tb[i][j] = tile[(qh + i * 8 + j) * 136 + dT];
  #pragma unroll
  for (int i = 0; i < 4; i++)
    *(bf16x8*)(hbT + (size_t)(h * DH + dT) * S + q0 + qh + i * 8) = tb[i];
}

// ---------------- embedding gather -> bf16 h, h^T, and landmark copies ----------------
__global__ __launch_bounds__(256) void embedT(const int* __restrict__ tokens,
                                              const float* __restrict__ emb,
                                              const int* __restrict__ lq,
                                              const unsigned long long* __restrict__ lmask,
                                              bf16_t* __restrict__ hb, bf16_t* __restrict__ hbT,
                                              bf16_t* __restrict__ hbL, bf16_t* __restrict__ hbLT) {
  __shared__ bf16_t tile[64 * 136];
  int tid = threadIdx.x;
  int q0 = blockIdx.x * 64, h = blockIdx.y;
  int ql = tid >> 2, d0 = (tid & 3) * 32;
  int tok = tokens[q0 + ql];
  const float4* src = (const float4*)(emb + (size_t)tok * HID + h * DH + d0);
  bf16x8 ob[4];
  #pragma unroll
  for (int i = 0; i < 8; i++) {
    float4 f = src[i];
    ob[i >> 1][(i & 1) * 4 + 0] = (bf16_t)f.x;
    ob[i >> 1][(i & 1) * 4 + 1] = (bf16_t)f.y;
    ob[i >> 1][(i & 1) * 4 + 2] = (bf16_t)f.z;
    ob[i >> 1][(i & 1) * 4 + 3] = (bf16_t)f.w;
  }
  store_h_hT(ob, tile, q0, h, ql, d0, tid, hb, hbT);
  unsigned long long lm = lmask[q0 >> 6];
  while (lm) {
    int r = __builtin_ctzll(lm);
    lm &= lm - 1;
    int li = lq[q0 + r];
    if (li >= 0 && tid < 128) {
      bf16_t vv = tile[r * 136 + tid];
      hbL[(size_t)li * HID + h * DH + tid] = vv;
      hbLT[((size_t)(h * DH + tid)) * LCAP + li] = vv;
    }
  }
}

// ---------------- fused attention layer: 1 wave / 32-q stripe, barrier-free ----------------
__global__ __launch_bounds__(64, 2) void attn7(const bf16_t* __restrict__ hb,
                                               const bf16_t* __restrict__ hbT,
                                               const bf16_t* __restrict__ hbL,
                                               const bf16_t* __restrict__ hbLT,
                                               const unsigned* __restrict__ cmask,
                                               const int4* __restrict__ mi,
                                               const int2* __restrict__ smeta,
                                               const int* __restrict__ lq,
                                               const unsigned long long* __restrict__ lmask,
                                               bf16_t* __restrict__ ob,
                                               bf16_t* __restrict__ obT,
                                               bf16_t* __restrict__ obL,
                                               bf16_t* __restrict__ obLT,
                                               int writeT) {
  __shared__ __align__(16) char lds_raw[32768];   // 2 bufs x (K 8KB + Vt 8KB)

  int h = blockIdx.x, st = blockIdx.y;            // st 0..63, 32 q each
  int2 sm = smeta[st];
  int nsT = sm.x, lcount = sm.y;
  int nNear = st + 1 - nsT;
  int nLT = (lcount + 31) >> 5;
  int nIter = nNear + nLT;

  int l = threadIdx.x, l31 = l & 31, hi = l >> 5;
  int q0 = 32 * st, q = q0 + l31;
  int npq = mi[q].x & 1;

  bf16x8 qf[8];
  {
    const bf16_t* hq = hb + (size_t)q * HID + h * DH;
    #pragma unroll
    for (int ks = 0; ks < 8; ks++) qf[ks] = *(const bf16x8*)(hq + ks * 16 + hi * 8);
  }

  f32x16 acc[4];
  #pragma unroll
  for (int i = 0; i < 4; i++)
    #pragma unroll
    for (int r = 0; r < 16; r++) acc[i][r] = 0.f;
  float m = -1e30f, lsum = 0.f;
  int swz = l31 & 7;

  auto STAGE = [&](int i, int b) {
    const bf16_t* Kbase; const bf16_t* Vbase; size_t Vstr;
    if (i < nNear) {
      int kv0 = (nsT + i) * 32;
      Kbase = hb + (size_t)kv0 * HID + h * DH;
      Vbase = hbT + (size_t)(h * DH) * S + kv0; Vstr = S;
    } else {
      int j0 = (i - nNear) * 32;
      Kbase = hbL + (size_t)j0 * HID + h * DH;
      Vbase = hbLT + (size_t)(h * DH) * LCAP + j0; Vstr = LCAP;
    }
    bf16_t* Kb = (bf16_t*)(lds_raw + b * 16384);
    bf16_t* Vb = (bf16_t*)(lds_raw + b * 16384 + 8192);
    #pragma unroll
    for (int i2 = 0; i2 < 8; i2++) {
      int rowK = i2 * 4 + (l >> 4); int chK = (l & 15) ^ (rowK & 7);
      gl_lds16(Kbase + (size_t)rowK * HID + chK * 8, Kb + i2 * 512);
    }
    #pragma unroll
    for (int i2 = 0; i2 < 8; i2++) {
      int rowV = i2 * 16 + (l >> 2); int chV = (l & 3) ^ (rowV & 3);
      gl_lds16(Vbase + (size_t)rowV * Vstr + chV * 8, Vb + i2 * 512);
    }
  };

  auto getmask = [&](int i) -> unsigned {
    if (i < nNear) return cmask[(size_t)(nsT + i) * S + q];
    int rem = lcount - (i - nNear) * 32;
    unsigned w0 = (rem >= 32) ? 0xffffffffu : ((rem <= 0) ? 0u : ((1u << rem) - 1u));
    return npq ? w0 : 0u;
  };

  STAGE(0, 0);
  for (int i = 0; i < nIter; i++) {
    int b = i & 1;
    if (i + 1 < nIter) {
      STAGE(i + 1, b ^ 1);
      asm volatile("s_waitcnt vmcnt(16)" ::: "memory");
    } else {
      asm volatile("s_waitcnt vmcnt(0)" ::: "memory");
    }
    unsigned w0 = getmask(i);

    if (__any(w0 != 0u)) {
      const bf16_t* Kb = (const bf16_t*)(lds_raw + b * 16384);
      const bf16_t* Vb = (const bf16_t*)(lds_raw + b * 16384 + 8192);
      f32x16 s;
      #pragma unroll
      for (int r = 0; r < 16; r++) s[r] = 0.f;
      const bf16_t* kp = Kb + l31 * 128;
      #pragma unroll
      for (int ks = 0; ks < 8; ks++) {
        bf16x8 kf = *(const bf16x8*)(kp + (((2 * ks + hi) ^ swz) * 8));
        s = MFMA32(kf, qf[ks], s, 0, 0, 0);
      }

      float sv[16];
      float mx = NEGS;
      #pragma unroll
      for (int r = 0; r < 16; r++) {
        int bit = (r & 3) + 8 * (r >> 2) + 4 * hi;
        sv[r] = ((w0 >> bit) & 1u) ? s[r] : NEGS;
        mx = fmaxf(mx, sv[r]);
      }
      mx = fmaxf(mx, __shfl_xor(mx, 32, 64));
      if (__any(mx > m + RTHR)) {
        float mn = fmaxf(m, mx);
        float al = exp2f((m - mn) * K2EXP);
        m = mn; lsum *= al;
        #pragma unroll
        for (int r = 0; r < 16; r++) {
          float alr = __shfl(al, (r & 3) + 8 * (r >> 2) + 4 * hi, 64);
          #pragma unroll
          for (int d = 0; d < 4; d++) acc[d][r] *= alr;
        }
      }
      float mk = m * K2EXP;
      float p[16], ps = 0.f;
      #pragma unroll
      for (int r = 0; r < 16; r++) {
        p[r] = exp2f(__builtin_fmaf(sv[r], K2EXP, -mk));
        ps += p[r];
      }
      ps += __shfl_xor(ps, 32, 64);
      lsum += ps;

      bf16x8 pa[2];
      {
        unsigned a0 = cvtpk(p[0], p[1]),   a1 = cvtpk(p[2], p[3]);
        unsigned b0 = cvtpk(p[4], p[5]),   b1 = cvtpk(p[6], p[7]);
        unsigned a2 = cvtpk(p[8], p[9]),   a3 = cvtpk(p[10], p[11]);
        unsigned b2 = cvtpk(p[12], p[13]), b3 = cvtpk(p[14], p[15]);
        plswap(a0, b0); plswap(a1, b1); plswap(a2, b2); plswap(a3, b3);
        pa[0] = mk8(a0, a1, b0, b1);
        pa[1] = mk8(a2, a3, b2, b3);
      }

      #pragma unroll
      for (int db = 0; db < 4; db++) {
        const bf16_t* vr = Vb + (32 * db + l31) * 32;
        #pragma unroll
        for (int ks = 0; ks < 2; ks++) {
          bf16x8 vf = *(const bf16x8*)(vr + (((2 * ks + hi) ^ (l31 & 3)) * 8));
          acc[db] = MFMA32(pa[ks], vf, acc[db], 0, 0, 0);
        }
      }
    }
  }

  // epilogue (single wave, DS ops are wave-ordered: no barriers needed)
  bf16_t* tl = (bf16_t*)lds_raw;   // 32 x 132 bf16 = 8.25 KB, aliases buf0 (all reads done)
  float inv = (lsum > 0.f) ? 1.f / lsum : 0.f;
  #pragma unroll
  for (int r = 0; r < 16; r++) {
    int qr = (r & 3) + 8 * (r >> 2) + 4 * hi;
    float ivr = __shfl(inv, qr, 64);
    #pragma unroll
    for (int db = 0; db < 4; db++)
      tl[qr * 132 + db * 32 + l31] = (bf16_t)(acc[db][r] * ivr);
  }
  {
    int row = l >> 1, hf = l & 1;
    #pragma unroll
    for (int k = 0; k < 8; k++) {
      bf16x8 v = *(const bf16x8*)(tl + row * 132 + hf * 64 + k * 8);
      *(bf16x8*)(ob + (size_t)(q0 + row) * HID + h * DH + hf * 64 + k * 8) = v;
    }
  }
  if (writeT) {
    #pragma unroll
    for (int half = 0; half < 2; half++) {
      int dd = l + 64 * half;
      #pragma unroll
      for (int c = 0; c < 4; c++) {
        bf16x8 v;
        #pragma unroll
        for (int e = 0; e < 8; e++) v[e] = tl[(c * 8 + e) * 132 + dd];
        *(bf16x8*)(obT + (size_t)(h * DH + dd) * S + q0 + c * 8) = v;
      }
    }
    unsigned lm32 = (unsigned)(lmask[st >> 1] >> ((st & 1) * 32));
    while (lm32) {
      int r = __builtin_ctz(lm32);
      lm32 &= lm32 - 1;
      int li = lq[q0 + r];
      if (li >= 0) {
        #pragma unroll
        for (int half = 0; half < 2; half++) {
          int dd = l + 64 * half;
          bf16_t vv = tl[r * 132 + dd];
          obL[(size_t)li * HID + h * DH + dd] = vv;
          obLT[((size_t)(h * DH + dd)) * LCAP + li] = vv;
        }
      }
    }
  }
}

// ---------------- lm head weight convert ----------------
__global__ __launch_bounds__(256) void wcvt(const float* __restrict__ w, bf16_t* __restrict__ wb) {
  int i = blockIdx.x * 256 + threadIdx.x;
  float4 f = ((const float4*)w)[i];
  bf16x4 v;
  v[0] = (bf16_t)f.x; v[1] = (bf16_t)f.y; v[2] = (bf16_t)f.z; v[3] = (bf16_t)f.w;
  *(bf16x4*)(wb + (size_t)i * 4) = v;
}

// ---------------- lm head + segment head fused ----------------
__global__ __launch_bounds__(256) void lmseg_head(const bf16_t* __restrict__ hb,
                                                  const bf16_t* __restrict__ wbf,
                                                  const float* __restrict__ bias,
                                                  const float* __restrict__ sw,
                                                  const float* __restrict__ sb,
                                                  float* __restrict__ out,
                                                  float* __restrict__ outseg) {
  __shared__ float red[4][16][130];
  int tid = threadIdx.x;
  int w = tid >> 6, l = tid & 63, l16 = l & 15, g = l >> 4;
  int t0 = blockIdx.x * 16;
  f32x4 acc[8];
  #pragma unroll
  for (int i = 0; i < 8; i++) acc[i] = (f32x4){0.f, 0.f, 0.f, 0.f};
  const bf16_t* arow = hb + (size_t)(t0 + l16) * HID + w * 512;
  for (int k0 = 0; k0 < 512; k0 += 32) {
    bf16x8 af = *(const bf16x8*)(arow + k0 + g * 8);
    #pragma unroll
    for (int vt = 0; vt < 8; vt++) {
      bf16x8 bf_ = *(const bf16x8*)(wbf + (size_t)(vt * 16 + l16) * HID + w * 512 + k0 + g * 8);
      acc[vt] = MFMA16(af, bf_, acc[vt], 0, 0, 0);
    }
  }
  #pragma unroll
  for (int vt = 0; vt < 8; vt++)
    #pragma unroll
    for (int r = 0; r < 4; r++)
      red[w][4 * g + r][vt * 16 + l16] = acc[vt][r];
  __syncthreads();
  int q = tid >> 4, vc = (tid & 15) * 8;
  #pragma unroll
  for (int j = 0; j < 8; j++) {
    float s = red[0][q][vc + j] + red[1][q][vc + j] + red[2][q][vc + j] + red[3][q][vc + j];
    out[(size_t)(t0 + q) * VOC + vc + j] = s + bias[vc + j];
  }
  {
    int c = tid & 15;
    const bf16_t* hrow = hb + (size_t)(t0 + q) * HID + c * 128;
    float s0 = 0.f, s1 = 0.f;
    #pragma unroll
    for (int i = 0; i < 16; i++) {
      bf16x8 v = *(const bf16x8*)(hrow + i * 8);
      const float4* w0p = (const float4*)(sw + c * 128 + i * 8);
      const float4* w1p = (const float4*)(sw + HID + c * 128 + i * 8);
      float4 x0 = w0p[0], x1 = w0p[1], y0 = w1p[0], y1 = w1p[1];
      s0 += (float)v[0]*x0.x + (float)v[1]*x0.y + (float)v[2]*x0.z + (float)v[3]*x0.w
          + (float)v[4]*x1.x + (float)v[5]*x1.y + (float)v[6]*x1.z + (float)v[7]*x1.w;
      s1 += (float)v[0]*y0.x + (float)v[1]*y0.y + (float)v[2]*y0.z + (float)v[3]*y0.w
          + (float)v[4]*y1.x + (float)v[5]*y1.y + (float)v[6]*y1.z + (float)v[7]*y1.w;
    }
    #pragma unroll
    for (int off = 1; off < 16; off <<= 1) {
      s0 += __shfl_xor(s0, off, 64);
      s1 += __shfl_xor(s1, off, 64);
    }
    if (c == 0) {
      outseg[(size_t)(t0 + q) * 2] = s0 + sb[0];
      outseg[(size_t)(t0 + q) * 2 + 1] = s1 + sb[1];
    }
  }
}

extern "C" void kernel_launch(void* const* d_in, const int* in_sizes, int n_in,
                              void* d_out, int out_size, void* d_ws, size_t ws_size,
                              hipStream_t stream) {
  const int* tokens = (const int*)d_in[0];
  const unsigned char* seg = (const unsigned char*)d_in[1];
  const unsigned char* spc = (const unsigned char*)d_in[2];
  const float* emb_w = (const float*)d_in[3];
  const float* lm_w = (const float*)d_in[4];
  const float* lm_b = (const float*)d_in[5];
  const float* seg_w = (const float*)d_in[6];
  const float* seg_b = (const float*)d_in[7];

  char* ws = (char*)d_ws;
  int4* mi = (int4*)ws;                                              // 32KB @0
  unsigned* cmask = (unsigned*)(ws + (1u << 20));                    // 512KB @1MB
  int* lq = (int*)(ws + (1u << 20) + (512u << 10));                  // 8KB
  unsigned long long* lmask = (unsigned long long*)(ws + (1u << 20) + (520u << 10)); // 256B
  int2* smeta = (int2*)(ws + (1u << 20) + (524u << 10));             // 512B
  bf16_t* wbf = (bf16_t*)(ws + (2u << 20));                          // 512KB @2MB
  bf16_t* hbLA  = (bf16_t*)(ws + (3u << 20));                        // 512KB @3MB
  bf16_t* hbLTA = (bf16_t*)(ws + (3u << 20) + (512u << 10));         // 512KB
  bf16_t* hbLB  = (bf16_t*)(ws + (4u << 20));                        // 512KB @4MB
  bf16_t* hbLTB = (bf16_t*)(ws + (4u << 20) + (512u << 10));         // 512KB
  bf16_t* hbA  = (bf16_t*)(ws + (8u << 20));                         // 8MB @8MB
  bf16_t* hbTA = (bf16_t*)(ws + (16u << 20));                        // 8MB @16MB
  bf16_t* hbB  = (bf16_t*)(ws + (24u << 20));                        // 8MB @24MB
  bf16_t* hbTB = (bf16_t*)(ws + (32u << 20));                        // 8MB @32MB
  float* out = (float*)d_out;

  maskprep2<<<1, 256, 0, stream>>>(tokens, seg, spc, mi, lq, lmask, smeta);
  bitgen<<<dim3(64, 8), 256, 0, stream>>>(mi, cmask);
  embedT<<<dim3(S / 64, NH), 256, 0, stream>>>(tokens, emb_w, lq, lmask, hbA, hbTA, hbLA, hbLTA);

  bf16_t* cur = hbA;   bf16_t* curT = hbTA;
  bf16_t* nxt = hbB;   bf16_t* nxtT = hbTB;
  bf16_t* curL = hbLA; bf16_t* curLT = hbLTA;
  bf16_t* nxtL = hbLB; bf16_t* nxtLT = hbLTB;
  for (int L = 0; L < 4; L++) {
    attn7<<<dim3(NH, 64), 64, 0, stream>>>(cur, curT, curL, curLT, cmask, mi, smeta, lq, lmask,
                                           nxt, nxtT, nxtL, nxtLT, (L < 3) ? 1 : 0);
    bf16_t* t1 = cur; cur = nxt; nxt = t1;
    bf16_t* t2 = curT; curT = nxtT; nxtT = t2;
    bf16_t* t3 = curL; curL = nxtL; nxtL = t3;
    bf16_t* t4 = curLT; curLT = nxtLT; nxtLT = t4;
  }

  wcvt<<<(VOC * HID / 4) / 256, 256, 0, stream>>>(lm_w, wbf);
  lmseg_head<<<S / 16, 256, 0, stream>>>(cur, wbf, lm_b, seg_w, seg_b, out, out + (size_t)S * VOC);
}

// Round 11
// 137.274 us; speedup vs baseline: 1.0753x; 1.0753x over previous
//
#include <hip/hip_runtime.h>

#define S 2048
#define HID 2048
#define NH 16
#define DH 128
#define VOC 128
#define LCAP 128
#define K2EXP 0.12752551286084112f   // (1/sqrt(128)) * log2(e)
#define RTHR 62.0f                   // defer-max threshold in raw-score units
#define NEGS -3.0e38f

typedef __bf16 bf16_t;
typedef __attribute__((ext_vector_type(8))) __bf16 bf16x8;
typedef __attribute__((ext_vector_type(4))) __bf16 bf16x4;
typedef __attribute__((ext_vector_type(4))) float f32x4;
typedef __attribute__((ext_vector_type(16))) float f32x16;

typedef __attribute__((address_space(1))) unsigned int guint;
typedef __attribute__((address_space(3))) unsigned int luint;

#define MFMA16 __builtin_amdgcn_mfma_f32_16x16x32_bf16
#define MFMA32 __builtin_amdgcn_mfma_f32_32x32x16_bf16

__device__ __forceinline__ void gl_lds16(const void* g, void* l) {
  __builtin_amdgcn_global_load_lds((guint*)(unsigned long long)g,
                                   (luint*)(unsigned)(unsigned long long)l,
                                   16, 0, 0);
}

__device__ __forceinline__ unsigned cvtpk(float lo, float hi) {
  unsigned r;
  asm("v_cvt_pk_bf16_f32 %0, %1, %2" : "=v"(r) : "v"(lo), "v"(hi));
  return r;
}
__device__ __forceinline__ void plswap(unsigned& a, unsigned& b) {
  asm volatile("v_permlane32_swap_b32 %0, %1" : "+v"(a), "+v"(b));
}
__device__ __forceinline__ bf16x8 mk8(unsigned d0, unsigned d1, unsigned d2, unsigned d3) {
  union { unsigned u[4]; bf16x8 v; } x;
  x.u[0] = d0; x.u[1] = d1; x.u[2] = d2; x.u[3] = d3;
  return x.v;
}

// vtb layout: per (head h, 32-kv tile t) a contiguous 4096-halfword block:
//   vtb[(h*64+t)*4096 + d*32 + c*8 + e] = h_hidden[kv = 32t + 8*(c^(d&3)) + e][h*DH + d]
// i.e. a verbatim image of the LDS Vb tile (chunk-XOR-swizzled V^T).

// ---------------- mask precompute: intervals + starts + landmarks + 32q-stripe meta ----------------
__global__ __launch_bounds__(256) void maskprep2(const int* __restrict__ tokens,
                                                 const unsigned char* __restrict__ seg,
                                                 const unsigned char* __restrict__ spc,
                                                 int4* __restrict__ mi,
                                                 int* __restrict__ lq,
                                                 unsigned long long* __restrict__ lmask,
                                                 int2* __restrict__ smeta) {
  __shared__ int ssp[257], ssg[257], smw[257], sms[257], sfl[257];
  __shared__ int fpre[2048];
  __shared__ int ns64[64];
  __shared__ unsigned long long lmk[32];
  __shared__ int cdet[2];
  int t = threadIdx.x;
  if (t < 2) cdet[t] = 0;
  if (t < 32) lmk[t] = 0ull;
  __syncthreads();
  {
    int nz = ((t & 3) != 0 && seg[t]) ? 1 : 0;
    int fc = ((t & 3) == 3 && seg[t] == 0x3f) ? 1 : 0;
    if (nz) atomicAdd(&cdet[0], 1);
    if (fc) atomicAdd(&cdet[1], 1);
  }
  __syncthreads();
  int lay = (cdet[1] > 8) ? 2 : ((cdet[0] > 4) ? 1 : 0);
  auto getb = [&](const unsigned char* p, int i) -> int {
    if (lay == 1) return p[i] != 0;
    if (lay == 2) return ((const float*)p)[i] != 0.f;
    return ((const int*)p)[i] != 0;
  };
  int base = t * 8;
  int spv[8], sgv[8], npv[8], fv[8];
  int a = 0, b = 0, mw = 0, ms = 0, fs = 0;
  for (int j = 0; j < 8; j++) {
    int i = base + j;
    spv[j] = getb(spc, i);
    sgv[j] = 1 - getb(seg, i);
    npv[j] = (tokens[i] != 127) ? 1 : 0;
    fv[j] = spv[j] & sgv[j] & npv[j];
    a += spv[j]; b += sgv[j]; fs += fv[j];
    if (i >= 1 && spv[j]) mw = (i + 1 > mw) ? i + 1 : mw;
    if (i >= 1 && sgv[j]) ms = (i + 1 > ms) ? i + 1 : ms;
  }
  ssp[t + 1] = a; ssg[t + 1] = b; smw[t + 1] = mw; sms[t + 1] = ms; sfl[t + 1] = fs;
  if (t == 0) { ssp[0] = 0; ssg[0] = 0; smw[0] = 0; sms[0] = 0; sfl[0] = 0; }
  __syncthreads();
  for (int off = 1; off < 256; off <<= 1) {
    int v0 = 0, v1 = 0, v2 = 0, v3 = 0, v4 = 0;
    if (t + 1 > off) { v0 = ssp[t+1-off]; v1 = ssg[t+1-off]; v2 = smw[t+1-off]; v3 = sms[t+1-off]; v4 = sfl[t+1-off]; }
    __syncthreads();
    ssp[t + 1] += v0; ssg[t + 1] += v1;
    if (v2 > smw[t + 1]) smw[t + 1] = v2;
    if (v3 > sms[t + 1]) sms[t + 1] = v3;
    sfl[t + 1] += v4;
    __syncthreads();
  }
  if ((t & 3) == 0) {
    int ws = smw[t], ss = sms[t];
    ns64[t >> 2] = ws < ss ? ws : ss;
  }
  int esp = ssp[t], esg = ssg[t], ef = sfl[t];
  for (int j = 0; j < 8; j++) {
    int i = base + j;
    int wint = (i == 0) ? (1 + spv[j]) : (1 + esp);
    int sint = (i == 0) ? (1 + sgv[j]) : (1 + esg);
    mi[i] = make_int4(npv[j] | (spv[j] << 1) | (sgv[j] << 2), wint, sint, 0);
    fpre[i] = ef;
    int lqv = (fv[j] && ef < LCAP) ? ef : -1;
    lq[i] = lqv;
    if (lqv >= 0) atomicOr(&lmk[i >> 6], 1ull << (i & 63));
    esp += spv[j]; esg += sgv[j]; ef += fv[j];
  }
  __syncthreads();
  if (t < 32) lmask[t] = lmk[t];
  if (t < 64) {
    int nsTile = ns64[t] >> 5;           // 32-kv tile index
    int lc = fpre[nsTile * 32];          // landmarks strictly below near zone
    if (lc > LCAP) lc = LCAP;
    smeta[t] = make_int2(nsTile, lc);
  }
}

// ---------------- full mask bit table: cmask[word][q], word=kv/32 ----------------
__global__ __launch_bounds__(256) void bitgen(const int4* __restrict__ mi,
                                              unsigned* __restrict__ cmask) {
  __shared__ int4 km[32];
  int w = blockIdx.x;
  int t = threadIdx.x;
  int q = blockIdx.y * 256 + t;
  if (t < 32) km[t] = mi[w * 32 + t];
  __syncthreads();
  int4 mq = mi[q];
  unsigned word = 0;
  #pragma unroll
  for (int j = 0; j < 32; j++) {
    int kv = w * 32 + j;
    int4 mk = km[j];
    bool v = ((mq.x & mk.x) & 1) &&
             ((mk.x & 2) || (mq.y == mk.y)) &&
             ((mk.x & 4) || (mq.z == mk.z)) &&
             (kv <= q);
    word |= (v ? 1u : 0u) << j;
  }
  cmask[(size_t)w * S + q] = word;
}

// ---------------- embedding gather -> bf16 hb + vtb tiles + landmark copies ----------------
__global__ __launch_bounds__(256) void embedT2(const int* __restrict__ tokens,
                                               const float* __restrict__ emb,
                                               const int* __restrict__ lq,
                                               const unsigned long long* __restrict__ lmask,
                                               bf16_t* __restrict__ hb, bf16_t* __restrict__ vtb,
                                               bf16_t* __restrict__ hbL, bf16_t* __restrict__ vtbL) {
  __shared__ bf16_t tile[64 * 136];
  int tid = threadIdx.x;
  int q0 = blockIdx.x * 64, h = blockIdx.y;
  int ql = tid >> 2, d0 = (tid & 3) * 32;
  int tok = tokens[q0 + ql];
  const float4* src = (const float4*)(emb + (size_t)tok * HID + h * DH + d0);
  bf16x8 ob[4];
  #pragma unroll
  for (int i = 0; i < 8; i++) {
    float4 f = src[i];
    ob[i >> 1][(i & 1) * 4 + 0] = (bf16_t)f.x;
    ob[i >> 1][(i & 1) * 4 + 1] = (bf16_t)f.y;
    ob[i >> 1][(i & 1) * 4 + 2] = (bf16_t)f.z;
    ob[i >> 1][(i & 1) * 4 + 3] = (bf16_t)f.w;
  }
  #pragma unroll
  for (int i = 0; i < 4; i++)
    *(bf16x8*)(hb + (size_t)(q0 + ql) * HID + h * DH + d0 + i * 8) = ob[i];
  #pragma unroll
  for (int i = 0; i < 4; i++)
    #pragma unroll
    for (int j = 0; j < 8; j++) tile[ql * 136 + d0 + i * 8 + j] = ob[i][j];
  __syncthreads();
  // vtb tiles: thread (tl = tid>>7, d = tid&127), writes d-row of the swizzled tile (coalesced 64B/thread)
  {
    int tl = tid >> 7, d = tid & 127;
    bf16_t* vt = vtb + ((size_t)(h * 64) + 2 * blockIdx.x + tl) * 4096;
    #pragma unroll
    for (int c = 0; c < 4; c++) {
      bf16x8 v;
      #pragma unroll
      for (int e = 0; e < 8; e++)
        v[e] = tile[(32 * tl + 8 * (c ^ (d & 3)) + e) * 136 + d];
      *(bf16x8*)(vt + d * 32 + c * 8) = v;
    }
  }
  // landmarks
  unsigned long long lm = lmask[q0 >> 6];
  while (lm) {
    int r = __builtin_ctzll(lm);
    lm &= lm - 1;
    int li = lq[q0 + r];
    if (li >= 0 && tid < 128) {
      bf16_t vv = tile[r * 136 + tid];
      hbL[(size_t)li * HID + h * DH + tid] = vv;
      vtbL[((size_t)(h * 4) + (li >> 5)) * 4096 + tid * 32 + (((li & 31) >> 3) ^ (tid & 3)) * 8 + (li & 7)] = vv;
    }
  }
}

// ---------------- fused attention layer: 1 wave / 32-q stripe, barrier-free, tiled V ----------------
__global__ __launch_bounds__(64, 2) void attn8(const bf16_t* __restrict__ hb,
                                               const bf16_t* __restrict__ vtb,
                                               const bf16_t* __restrict__ hbL,
                                               const bf16_t* __restrict__ vtbL,
                                               const unsigned* __restrict__ cmask,
                                               const int4* __restrict__ mi,
                                               const int2* __restrict__ smeta,
                                               const int* __restrict__ lq,
                                               const unsigned long long* __restrict__ lmask,
                                               bf16_t* __restrict__ ob,
                                               bf16_t* __restrict__ ovtb,
                                               bf16_t* __restrict__ obL,
                                               bf16_t* __restrict__ ovtbL,
                                               int writeT) {
  __shared__ __align__(16) char lds_raw[32768];   // 2 bufs x (K 8KB + Vt 8KB)

  int h = blockIdx.x, st = blockIdx.y;            // st 0..63, 32 q each
  int2 sm = smeta[st];
  int nsT = sm.x, lcount = sm.y;
  int nNear = st + 1 - nsT;
  int nLT = (lcount + 31) >> 5;
  int nIter = nNear + nLT;

  int l = threadIdx.x, l31 = l & 31, hi = l >> 5;
  int q0 = 32 * st, q = q0 + l31;
  int npq = mi[q].x & 1;

  bf16x8 qf[8];
  {
    const bf16_t* hq = hb + (size_t)q * HID + h * DH;
    #pragma unroll
    for (int ks = 0; ks < 8; ks++) qf[ks] = *(const bf16x8*)(hq + ks * 16 + hi * 8);
  }

  f32x16 acc[4];
  #pragma unroll
  for (int i = 0; i < 4; i++)
    #pragma unroll
    for (int r = 0; r < 16; r++) acc[i][r] = 0.f;
  float m = -1e30f, lsum = 0.f;
  int swz = l31 & 7;

  auto STAGE = [&](int i, int b) {
    const bf16_t* Kbase; const bf16_t* Vtile;
    if (i < nNear) {
      int t = nsT + i;
      Kbase = hb + (size_t)(t * 32) * HID + h * DH;
      Vtile = vtb + ((size_t)(h * 64) + t) * 4096;
    } else {
      int j = i - nNear;
      Kbase = hbL + (size_t)(j * 32) * HID + h * DH;
      Vtile = vtbL + ((size_t)(h * 4) + j) * 4096;
    }
    bf16_t* Kb = (bf16_t*)(lds_raw + b * 16384);
    bf16_t* Vb = (bf16_t*)(lds_raw + b * 16384 + 8192);
    #pragma unroll
    for (int i2 = 0; i2 < 8; i2++) {
      int rowK = i2 * 4 + (l >> 4); int chK = (l & 15) ^ (rowK & 7);
      gl_lds16(Kbase + (size_t)rowK * HID + chK * 8, Kb + i2 * 512);
    }
    #pragma unroll
    for (int i2 = 0; i2 < 8; i2++)
      gl_lds16(Vtile + i2 * 512 + l * 8, Vb + i2 * 512);
  };

  auto getmask = [&](int i) -> unsigned {
    if (i < nNear) return cmask[(size_t)(nsT + i) * S + q];
    int rem = lcount - (i - nNear) * 32;
    unsigned w0 = (rem >= 32) ? 0xffffffffu : ((rem <= 0) ? 0u : ((1u << rem) - 1u));
    return npq ? w0 : 0u;
  };

  STAGE(0, 0);
  for (int i = 0; i < nIter; i++) {
    int b = i & 1;
    if (i + 1 < nIter) {
      STAGE(i + 1, b ^ 1);
      asm volatile("s_waitcnt vmcnt(16)" ::: "memory");
    } else {
      asm volatile("s_waitcnt vmcnt(0)" ::: "memory");
    }
    unsigned w0 = getmask(i);

    if (__any(w0 != 0u)) {
      const bf16_t* Kb = (const bf16_t*)(lds_raw + b * 16384);
      const bf16_t* Vb = (const bf16_t*)(lds_raw + b * 16384 + 8192);
      f32x16 s;
      #pragma unroll
      for (int r = 0; r < 16; r++) s[r] = 0.f;
      const bf16_t* kp = Kb + l31 * 128;
      #pragma unroll
      for (int ks = 0; ks < 8; ks++) {
        bf16x8 kf = *(const bf16x8*)(kp + (((2 * ks + hi) ^ swz) * 8));
        s = MFMA32(kf, qf[ks], s, 0, 0, 0);
      }

      float sv[16];
      float mx = NEGS;
      #pragma unroll
      for (int r = 0; r < 16; r++) {
        int bit = (r & 3) + 8 * (r >> 2) + 4 * hi;
        sv[r] = ((w0 >> bit) & 1u) ? s[r] : NEGS;
        mx = fmaxf(mx, sv[r]);
      }
      mx = fmaxf(mx, __shfl_xor(mx, 32, 64));
      if (__any(mx > m + RTHR)) {
        float mn = fmaxf(m, mx);
        float al = exp2f((m - mn) * K2EXP);
        m = mn; lsum *= al;
        #pragma unroll
        for (int r = 0; r < 16; r++) {
          float alr = __shfl(al, (r & 3) + 8 * (r >> 2) + 4 * hi, 64);
          #pragma unroll
          for (int d = 0; d < 4; d++) acc[d][r] *= alr;
        }
      }
      float mk = m * K2EXP;
      float p[16], ps = 0.f;
      #pragma unroll
      for (int r = 0; r < 16; r++) {
        p[r] = exp2f(__builtin_fmaf(sv[r], K2EXP, -mk));
        ps += p[r];
      }
      ps += __shfl_xor(ps, 32, 64);
      lsum += ps;

      bf16x8 pa[2];
      {
        unsigned a0 = cvtpk(p[0], p[1]),   a1 = cvtpk(p[2], p[3]);
        unsigned b0 = cvtpk(p[4], p[5]),   b1 = cvtpk(p[6], p[7]);
        unsigned a2 = cvtpk(p[8], p[9]),   a3 = cvtpk(p[10], p[11]);
        unsigned b2 = cvtpk(p[12], p[13]), b3 = cvtpk(p[14], p[15]);
        plswap(a0, b0); plswap(a1, b1); plswap(a2, b2); plswap(a3, b3);
        pa[0] = mk8(a0, a1, b0, b1);
        pa[1] = mk8(a2, a3, b2, b3);
      }

      #pragma unroll
      for (int db = 0; db < 4; db++) {
        const bf16_t* vr = Vb + (32 * db + l31) * 32;
        #pragma unroll
        for (int ks = 0; ks < 2; ks++) {
          bf16x8 vf = *(const bf16x8*)(vr + (((2 * ks + hi) ^ (l31 & 3)) * 8));
          acc[db] = MFMA32(pa[ks], vf, acc[db], 0, 0, 0);
        }
      }
    }
  }

  // epilogue (single wave, DS ops wave-ordered: no barriers)
  bf16_t* tl = (bf16_t*)lds_raw;   // 32 x 132 bf16
  float inv = (lsum > 0.f) ? 1.f / lsum : 0.f;
  #pragma unroll
  for (int r = 0; r < 16; r++) {
    int qr = (r & 3) + 8 * (r >> 2) + 4 * hi;
    float ivr = __shfl(inv, qr, 64);
    #pragma unroll
    for (int db = 0; db < 4; db++)
      tl[qr * 132 + db * 32 + l31] = (bf16_t)(acc[db][r] * ivr);
  }
  // hb write: 4-lane x 64B groups per row (256B transactions)
  {
    int c4 = l & 3;
    #pragma unroll
    for (int g = 0; g < 2; g++) {
      int row = g * 16 + (l >> 2);
      #pragma unroll
      for (int k = 0; k < 4; k++) {
        bf16x8 v = *(const bf16x8*)(tl + row * 132 + c4 * 32 + k * 8);
        *(bf16x8*)(ob + (size_t)(q0 + row) * HID + h * DH + c4 * 32 + k * 8) = v;
      }
    }
  }
  if (writeT) {
    // vtb tile for stripe st: 8 coalesced 1KB segments
    bf16_t* vt = ovtb + ((size_t)(h * 64) + st) * 4096;
    #pragma unroll
    for (int s = 0; s < 8; s++) {
      int d = s * 16 + (l >> 2);
      bf16x8 v;
      #pragma unroll
      for (int e = 0; e < 8; e++)
        v[e] = tl[(8 * ((l & 3) ^ (d & 3)) + e) * 132 + d];
      *(bf16x8*)(vt + s * 512 + l * 8) = v;
    }
    // landmark rows
    unsigned lm32 = (unsigned)(lmask[st >> 1] >> ((st & 1) * 32));
    while (lm32) {
      int r = __builtin_ctz(lm32);
      lm32 &= lm32 - 1;
      int li = lq[q0 + r];
      if (li >= 0) {
        #pragma unroll
        for (int half = 0; half < 2; half++) {
          int dd = l + 64 * half;
          bf16_t vv = tl[r * 132 + dd];
          obL[(size_t)li * HID + h * DH + dd] = vv;
          ovtbL[((size_t)(h * 4) + (li >> 5)) * 4096 + dd * 32 + (((li & 31) >> 3) ^ (dd & 3)) * 8 + (li & 7)] = vv;
        }
      }
    }
  }
}

// ---------------- lm head weight convert ----------------
__global__ __launch_bounds__(256) void wcvt(const float* __restrict__ w, bf16_t* __restrict__ wb) {
  int i = blockIdx.x * 256 + threadIdx.x;
  float4 f = ((const float4*)w)[i];
  bf16x4 v;
  v[0] = (bf16_t)f.x; v[1] = (bf16_t)f.y; v[2] = (bf16_t)f.z; v[3] = (bf16_t)f.w;
  *(bf16x4*)(wb + (size_t)i * 4) = v;
}

// ---------------- lm head + segment head fused ----------------
__global__ __launch_bounds__(256) void lmseg_head(const bf16_t* __restrict__ hb,
                                                  const bf16_t* __restrict__ wbf,
                                                  const float* __restrict__ bias,
                                                  const float* __restrict__ sw,
                                                  const float* __restrict__ sb,
                                                  float* __restrict__ out,
                                                  float* __restrict__ outseg) {
  __shared__ float red[4][16][130];
  int tid = threadIdx.x;
  int w = tid >> 6, l = tid & 63, l16 = l & 15, g = l >> 4;
  int t0 = blockIdx.x * 16;
  f32x4 acc[8];
  #pragma unroll
  for (int i = 0; i < 8; i++) acc[i] = (f32x4){0.f, 0.f, 0.f, 0.f};
  const bf16_t* arow = hb + (size_t)(t0 + l16) * HID + w * 512;
  for (int k0 = 0; k0 < 512; k0 += 32) {
    bf16x8 af = *(const bf16x8*)(arow + k0 + g * 8);
    #pragma unroll
    for (int vt = 0; vt < 8; vt++) {
      bf16x8 bf_ = *(const bf16x8*)(wbf + (size_t)(vt * 16 + l16) * HID + w * 512 + k0 + g * 8);
      acc[vt] = MFMA16(af, bf_, acc[vt], 0, 0, 0);
    }
  }
  #pragma unroll
  for (int vt = 0; vt < 8; vt++)
    #pragma unroll
    for (int r = 0; r < 4; r++)
      red[w][4 * g + r][vt * 16 + l16] = acc[vt][r];
  __syncthreads();
  int q = tid >> 4, vc = (tid & 15) * 8;
  #pragma unroll
  for (int j = 0; j < 8; j++) {
    float s = red[0][q][vc + j] + red[1][q][vc + j] + red[2][q][vc + j] + red[3][q][vc + j];
    out[(size_t)(t0 + q) * VOC + vc + j] = s + bias[vc + j];
  }
  {
    int c = tid & 15;
    const bf16_t* hrow = hb + (size_t)(t0 + q) * HID + c * 128;
    float s0 = 0.f, s1 = 0.f;
    #pragma unroll
    for (int i = 0; i < 16; i++) {
      bf16x8 v = *(const bf16x8*)(hrow + i * 8);
      const float4* w0p = (const float4*)(sw + c * 128 + i * 8);
      const float4* w1p = (const float4*)(sw + HID + c * 128 + i * 8);
      float4 x0 = w0p[0], x1 = w0p[1], y0 = w1p[0], y1 = w1p[1];
      s0 += (float)v[0]*x0.x + (float)v[1]*x0.y + (float)v[2]*x0.z + (float)v[3]*x0.w
          + (float)v[4]*x1.x + (float)v[5]*x1.y + (float)v[6]*x1.z + (float)v[7]*x1.w;
      s1 += (float)v[0]*y0.x + (float)v[1]*y0.y + (float)v[2]*y0.z + (float)v[3]*y0.w
          + (float)v[4]*y1.x + (float)v[5]*y1.y + (float)v[6]*y1.z + (float)v[7]*y1.w;
    }
    #pragma unroll
    for (int off = 1; off < 16; off <<= 1) {
      s0 += __shfl_xor(s0, off, 64);
      s1 += __shfl_xor(s1, off, 64);
    }
    if (c == 0) {
      outseg[(size_t)(t0 + q) * 2] = s0 + sb[0];
      outseg[(size_t)(t0 + q) * 2 + 1] = s1 + sb[1];
    }
  }
}

extern "C" void kernel_launch(void* const* d_in, const int* in_sizes, int n_in,
                              void* d_out, int out_size, void* d_ws, size_t ws_size,
                              hipStream_t stream) {
  const int* tokens = (const int*)d_in[0];
  const unsigned char* seg = (const unsigned char*)d_in[1];
  const unsigned char* spc = (const unsigned char*)d_in[2];
  const float* emb_w = (const float*)d_in[3];
  const float* lm_w = (const float*)d_in[4];
  const float* lm_b = (const float*)d_in[5];
  const float* seg_w = (const float*)d_in[6];
  const float* seg_b = (const float*)d_in[7];

  char* ws = (char*)d_ws;
  int4* mi = (int4*)ws;                                              // 32KB @0
  unsigned* cmask = (unsigned*)(ws + (1u << 20));                    // 512KB @1MB
  int* lq = (int*)(ws + (1u << 20) + (512u << 10));                  // 8KB
  unsigned long long* lmask = (unsigned long long*)(ws + (1u << 20) + (520u << 10)); // 256B
  int2* smeta = (int2*)(ws + (1u << 20) + (524u << 10));             // 512B
  bf16_t* wbf = (bf16_t*)(ws + (2u << 20));                          // 512KB @2MB
  bf16_t* hbLA  = (bf16_t*)(ws + (3u << 20));                        // 512KB @3MB
  bf16_t* hbLB  = (bf16_t*)(ws + (3u << 20) + (512u << 10));         // 512KB
  bf16_t* vtbLA = (bf16_t*)(ws + (4u << 20));                        // 512KB @4MB
  bf16_t* vtbLB = (bf16_t*)(ws + (4u << 20) + (512u << 10));         // 512KB
  bf16_t* hbA  = (bf16_t*)(ws + (8u << 20));                         // 8MB @8MB
  bf16_t* hbB  = (bf16_t*)(ws + (16u << 20));                        // 8MB @16MB
  bf16_t* vtbA = (bf16_t*)(ws + (24u << 20));                        // 8MB @24MB
  bf16_t* vtbB = (bf16_t*)(ws + (32u << 20));                        // 8MB @32MB
  float* out = (float*)d_out;

  maskprep2<<<1, 256, 0, stream>>>(tokens, seg, spc, mi, lq, lmask, smeta);
  bitgen<<<dim3(64, 8), 256, 0, stream>>>(mi, cmask);
  embedT2<<<dim3(S / 64, NH), 256, 0, stream>>>(tokens, emb_w, lq, lmask, hbA, vtbA, hbLA, vtbLA);

  bf16_t* cur = hbA;   bf16_t* curV = vtbA;
  bf16_t* nxt = hbB;   bf16_t* nxtV = vtbB;
  bf16_t* curL = hbLA; bf16_t* curLV = vtbLA;
  bf16_t* nxtL = hbLB; bf16_t* nxtLV = vtbLB;
  for (int L = 0; L < 4; L++) {
    attn8<<<dim3(NH, 64), 64, 0, stream>>>(cur, curV, curL, curLV, cmask, mi, smeta, lq, lmask,
                                           nxt, nxtV, nxtL, nxtLV, (L < 3) ? 1 : 0);
    bf16_t* t1 = cur; cur = nxt; nxt = t1;
    bf16_t* t2 = curV; curV = nxtV; nxtV = t2;
    bf16_t* t3 = curL; curL = nxtL; nxtL = t3;
    bf16_t* t4 = curLV; curLV = nxtLV; nxtLV = t4;
  }

  wcvt<<<(VOC * HID / 4) / 256, 256, 0, stream>>>(lm_w, wbf);
  lmseg_head<<<S / 16, 256, 0, stream>>>(cur, wbf, lm_b, seg_w, seg_b, out, out + (size_t)S * VOC);
}